// Round 19
// baseline (59.770 us; speedup 1.0000x reference)
//
#include <hip/hip_runtime.h>
#include <hip/hip_bf16.h>

#define NN 512
#define FD 256
#define FI 128

typedef __attribute__((ext_vector_type(2))) float f2;

// workspace layout (float offsets)
#define OFF_AIN   0          // 2048*128  A_in = Uin x + biasIn
#define OFF_D     262144     // 2048*128  D    = -(Uout x + biasOut)
#define OFF_UINT  524288     // 64*128*4  (We1@Wi)^T packed [d4][g][4]
#define OFF_UOUTT 557056     // 64*128*4  (We1@Wo)^T packed [d4][g][4]
#define OFF_COEF  589824     // 32*16     per-gq packed {w0[4], w1[4], v[4], pad}
#define OFF_BIAS  590336     // 256       biasIn[128], biasOut[128]
#define OFF_PART  590592     // 1024*32   per-(b,jt,ir) partial maxes
#define OFF_WN2T  623360     // 64*256*4  Wn2 packed [d4][e][4]
// total 688896 floats = 2.63 MB

__device__ __forceinline__ f2 pk_fma(f2 a, f2 b, f2 c) {
    return __builtin_elementwise_fma(a, b, c);
}

// ---- kernel 1: fold U^T (packed [d4][g][4]) + pack Wn2 ----------------------
__global__ __launch_bounds__(256) void prep_kernel(
    const float* __restrict__ Wp,  const float* __restrict__ bp,
    const float* __restrict__ Wi,  const float* __restrict__ bi,
    const float* __restrict__ Wo,  const float* __restrict__ bo,
    const float* __restrict__ We1, const float* __restrict__ be1,
    const float* __restrict__ We2, const float* __restrict__ Wn2,
    float* ws)
{
    int bidx = blockIdx.x;
    int d = threadIdx.x;
    if (bidx >= 256) {                         // Wn2 transpose-pack
        int e = bidx - 256;                    // e in 0..255
        float v = Wn2[e * FD + d];             // coalesced row read
        ws[OFF_WN2T + (d >> 2) * (FD * 4) + e * 4 + (d & 3)] = v;
        return;
    }
    int io = bidx >> 7, g = bidx & 127;
    const float* W = io ? Wo : Wi;
    const float* wrow = We1 + g * FI;          // wave-uniform -> s_loads
    float acc = 0.f;
    for (int f = 0; f < FI; ++f)
        acc = __fmaf_rn(wrow[f], W[f * FD + d], acc);   // coalesced over d
    // packed layout [d4][g][4]
    ws[(io ? OFF_UOUTT : OFF_UINT) + (d >> 2) * (FI * 4) + g * 4 + (d & 3)] = acc;

    if (bidx == 0 && d < FI) {
        const float* wr = We1 + d * FI;
        float a0 = 0.f, a1 = 0.f, abi = 0.f, abo = 0.f;
        for (int f = 0; f < FI; ++f) {
            float w = wr[f];
            a0  = __fmaf_rn(w, Wp[f * 2 + 0], a0);
            a1  = __fmaf_rn(w, Wp[f * 2 + 1], a1);
            abi = __fmaf_rn(w, bi[f] + bp[f], abi);
            abo = __fmaf_rn(w, bo[f], abo);
        }
        int gq = d >> 2, k = d & 3;
        ws[OFF_COEF + gq * 16 + k]     = a0;
        ws[OFF_COEF + gq * 16 + 4 + k] = a1;
        ws[OFF_COEF + gq * 16 + 8 + k] = We2[d];
        ws[OFF_BIAS + d]       = abi + be1[d];
        ws[OFF_BIAS + 128 + d] = abo;
    }
}

// ---- kernel 2: node projections A/D — g-split, U read once per block --------
// 512 blocks = 256 node-octets x 2 g-halves; 256 thr; 2 blk/CU
__global__ __launch_bounds__(256) void proj_kernel(
    const float* __restrict__ x, float* ws)
{
    __shared__ __align__(16) float xs[8][FD];   // 8 KB
    int t  = threadIdx.x;
    int nb = (blockIdx.x >> 1) * 8;
    int h  = blockIdx.x & 1;
    ((float4*)xs)[t]       = ((const float4*)(x + nb * FD))[t];
    ((float4*)xs)[t + 256] = ((const float4*)(x + nb * FD))[t + 256];
    __syncthreads();

    int gl = t & 63, io = (t >> 6) & 1, nh = t >> 7;
    int g = h * 64 + gl;
    const float4* U4 = (const float4*)(ws + (io ? OFF_UOUTT : OFF_UINT));
    float bias = ws[OFF_BIAS + io * 128 + g];
    f2 acc[4];
    #pragma unroll
    for (int n = 0; n < 4; ++n) acc[n] = (f2)(0.f);

    #pragma unroll 4
    for (int d4 = 0; d4 < FD / 4; ++d4) {
        float4 u = U4[d4 * FI + g];            // coalesced 1 KB per wave
        f2 u01 = {u.x, u.y}, u23 = {u.z, u.w};
        #pragma unroll
        for (int n = 0; n < 4; ++n) {
            float4 xv = *(const float4*)(&xs[nh * 4 + n][d4 * 4]);  // bcast
            f2 x01 = {xv.x, xv.y}, x23 = {xv.z, xv.w};
            acc[n] = pk_fma(u01, x01, acc[n]);
            acc[n] = pk_fma(u23, x23, acc[n]);
        }
    }

    float sgn = io ? -1.f : 1.f;
    float* dst = ws + (io ? OFF_D : OFF_AIN);
    #pragma unroll
    for (int n = 0; n < 4; ++n)
        dst[(nb + nh * 4 + n) * FI + g] = sgn * (acc[n].x + acc[n].y + bias);
}

// ---- kernel 3: edge MLP on ACTIVE edges (batched-rcp sigmoid gelu) ----------
// 1024 blocks = 4b * 16jt * 16ir; tile = 32 i-rows x 32 j-cols; 512 threads
__global__ __launch_bounds__(512) void edge_kernel(
    const float* __restrict__ pos, const float* __restrict__ sup,
    const float* __restrict__ Ain, const float* __restrict__ Dmat,
    const float* __restrict__ coef, const float* __restrict__ be2p,
    float* __restrict__ part)
{
    __shared__ __align__(16) float sD[32 * 128];   // 16 KB, swizzle (r&31)<<2
    __shared__ __align__(16) float sA[32 * 128];   // 16 KB, swizzle (r&31)<<2
    __shared__ unsigned short sList[1024];         // 2 KB active-edge list
    __shared__ int smax[32];                       // per-j col max (float bits)
    __shared__ int scnt;                           // ~34.2 KB total

    int tile = blockIdx.x;
    int ir = tile & 15, jt = (tile >> 4) & 15, b = tile >> 8;  // 16*16*4 = 1024
    int tid = threadIdx.x;
    int lane = tid & 63;

    // stage D (32 j-rows): word = r*128 + (c ^ ((r&31)<<2))  [bijective in-row]
    const float4* Dg4 = (const float4*)(Dmat + (b * NN + jt * 32) * FI);
    #pragma unroll
    for (int k = 0; k < 2; ++k) {
        int s = tid + k * 512;
        float4 v = Dg4[s];
        int r = s >> 5, c = (s & 31) * 4;
        *(float4*)(sD + r * 128 + (c ^ ((r & 31) << 2))) = v;
    }
    // stage A (32 i-rows)
    const float4* Ag4 = (const float4*)(Ain + (b * NN + ir * 32) * FI);
    #pragma unroll
    for (int k = 0; k < 2; ++k) {
        int s = tid + k * 512;
        float4 v = Ag4[s];
        int r = s >> 5, c = (s & 31) * 4;
        *(float4*)(sA + r * 128 + (c ^ ((r & 31) << 2))) = v;
    }
    if (tid < 32) smax[tid] = 0;   // 0.0f == exact value of suppressed edges
    if (tid == 0) scnt = 0;
    __syncthreads();

    // compaction: 1024 candidates in 2 rounds; entries j-contiguous per i-row
    const float* S = sup + (size_t)(b * NN + ir * 32) * NN + jt * 32;
    #pragma unroll
    for (int k = 0; k < 2; ++k) {
        int s = tid + k * 512;
        int i_l = s >> 5, j_l = s & 31;
        bool act = (S[i_l * NN + j_l] != 0.f);
        unsigned long long mask = __ballot(act);
        int wbase = 0;
        if (lane == 0 && mask) wbase = atomicAdd(&scnt, (int)__popcll(mask));
        wbase = __shfl(wbase, 0);
        if (act) {
            int prefix = (int)__popcll(mask & ((1ull << lane) - 1ull));
            sList[wbase + prefix] = (unsigned short)s;
        }
    }
    __syncthreads();

    int cnt = scnt;
    float be2 = *be2p;
    const float2* pos2 = (const float2*)pos;

    for (int r = tid; r < cnt; r += 512) {
        int e = (int)sList[r];
        int i_l = e >> 5, j_l = e & 31;
        float2 pp = pos2[(size_t)(b * NN + ir * 32 + i_l) * NN + jt * 32 + j_l];
        const float* Ar = sA + i_l * 128;
        const float* Dr = sD + j_l * 128;
        int aswz = i_l << 2;           // i_l < 32
        int dswz = j_l << 2;           // j_l < 32
        f2 px = {pp.x, pp.x}, py = {pp.y, pp.y};
        f2 z01 = {0.f, 0.f}, z23 = {0.f, 0.f};
        #pragma unroll 4
        for (int gq = 0; gq < 32; ++gq) {
            float4 a  = *(const float4*)(Ar + ((gq * 4) ^ aswz));
            float4 d  = *(const float4*)(Dr + ((gq * 4) ^ dswz));
            // wave-uniform, loop-uniform -> s_load_dwordx4 into SGPRs
            float4 w0 = *(const float4*)(coef + gq * 16);
            float4 w1 = *(const float4*)(coef + gq * 16 + 4);
            float4 vv = *(const float4*)(coef + gq * 16 + 8);
            f2 a01 = {a.x, a.y}, a23 = {a.z, a.w};
            f2 d01 = {d.x, d.y}, d23 = {d.z, d.w};
            f2 w001 = {w0.x, w0.y}, w023 = {w0.z, w0.w};
            f2 w101 = {w1.x, w1.y}, w123 = {w1.z, w1.w};
            f2 v01 = {vv.x, vv.y}, v23 = {vv.z, vv.w};
            f2 y01 = pk_fma(w101, py, pk_fma(w001, px, a01 + d01));
            f2 y23 = pk_fma(w123, py, pk_fma(w023, px, a23 + d23));
            // gelu(y) = y - y/(1+2^zs), zs = y*(2.3022 + 0.10294 y^2),
            // batched reciprocal: one v_rcp for all 4 denominators.
            f2 sa = pk_fma(y01 * y01, (f2)(0.10294325f), (f2)(2.3022083f));
            f2 sb = pk_fma(y23 * y23, (f2)(0.10294325f), (f2)(2.3022083f));
            f2 za = __builtin_elementwise_min(y01 * sa, (f2)(30.0f));
            f2 zb = __builtin_elementwise_min(y23 * sb, (f2)(30.0f));
            f2 ea, eb;
            ea.x = __builtin_amdgcn_exp2f(za.x);
            ea.y = __builtin_amdgcn_exp2f(za.y);
            eb.x = __builtin_amdgcn_exp2f(zb.x);
            eb.y = __builtin_amdgcn_exp2f(zb.y);
            f2 da = ea + (f2)(1.0f);            // each in [1, ~1.07e9]
            f2 db = eb + (f2)(1.0f);
            f2 q  = da * db;                    // {d1*d3, d2*d4}
            float R = __builtin_amdgcn_rcpf(q.x * q.y);   // 1/(d1 d2 d3 d4)
            f2 qs = {q.y, q.x};
            f2 Rq = qs * (f2)(R);               // {R d2d4, R d1d3}
            f2 ra = Rq * db;                    // {1/d1, 1/d2}
            f2 rb = Rq * da;                    // {1/d3, 1/d4}
            f2 ga = pk_fma(-y01, ra, y01);
            f2 gb = pk_fma(-y23, rb, y23);
            z01 = pk_fma(v01, ga, z01);
            z23 = pk_fma(v23, gb, z23);
        }
        float z = (z01.x + z01.y) + (z23.x + z23.y);
        // positive floats order-preserve as signed ints; negatives < 0 == init
        atomicMax(&smax[j_l], __float_as_int(z + be2));
    }
    __syncthreads();
    if (tid < 32)
        part[tile * 32 + tid] = __int_as_float(smax[tid]);
}

// ---- kernel 4: reduce 16 i-range partials + node FFN (packed-Wn2 reads) -----
// 512 blocks * 4 nodes
__global__ __launch_bounds__(256) void final_kernel(
    const float* __restrict__ Wn1, const float* __restrict__ bn1,
    const float* __restrict__ wtx, const float* __restrict__ bn2,
    const float* __restrict__ part, float* __restrict__ out)
{
    __shared__ float red[4][17];
    __shared__ float nm[4];
    __shared__ __align__(16) float h1[4][FD];
    int nb = blockIdx.x * 4;                  // 512 blocks * 4 nodes
    int b  = nb >> 9;
    int j0 = nb & 511;
    int jt = j0 >> 5, jl0 = j0 & 31;          // 4-aligned j0 stays in one jt
    int t = threadIdx.x;
    if (t < 64) {
        int k = t & 3, ir = t >> 2;           // ir in 0..15
        red[k][ir] = part[(((b * 16 + jt) * 16) + ir) * 32 + jl0 + k];
    }
    __syncthreads();
    if (t < 4) {
        float m2 = red[t][0];
        #pragma unroll
        for (int q = 1; q < 16; ++q) m2 = fmaxf(m2, red[t][q]);
        nm[t] = m2;
    }
    __syncthreads();
    {
        float wv = Wn1[t];        // Wn1 shape [256,1]
        float bv = bn1[t];
        #pragma unroll
        for (int n = 0; n < 4; ++n)
            h1[n][t] = fmaxf(0.f, __fmaf_rn(nm[n], wv, bv));
    }
    __syncthreads();
    float acc[4] = {0.f, 0.f, 0.f, 0.f};
    const float4* WX = (const float4*)wtx;    // [d4][e]
    #pragma unroll 4
    for (int d4 = 0; d4 < FD / 4; ++d4) {
        float4 w = WX[d4 * FD + t];           // coalesced 1 KB per wave
        #pragma unroll
        for (int n = 0; n < 4; ++n) {
            float4 hv = *(const float4*)(&h1[n][d4 * 4]);  // broadcast (free)
            acc[n] = __fmaf_rn(w.x, hv.x, acc[n]);
            acc[n] = __fmaf_rn(w.y, hv.y, acc[n]);
            acc[n] = __fmaf_rn(w.z, hv.z, acc[n]);
            acc[n] = __fmaf_rn(w.w, hv.w, acc[n]);
        }
    }
    float bb = bn2[t];
    #pragma unroll
    for (int n = 0; n < 4; ++n)
        out[(size_t)(nb + n) * FD + t] = fmaxf(0.f, acc[n] + bb);
}

extern "C" void kernel_launch(void* const* d_in, const int* in_sizes, int n_in,
                              void* d_out, int out_size, void* d_ws, size_t ws_size,
                              hipStream_t stream) {
    (void)in_sizes; (void)n_in; (void)out_size; (void)ws_size;
    const float* node = (const float*)d_in[0];
    const float* sup  = (const float*)d_in[1];
    const float* pos  = (const float*)d_in[2];
    const float* Wp   = (const float*)d_in[3];
    const float* bp   = (const float*)d_in[4];
    const float* Wi   = (const float*)d_in[5];
    const float* bi   = (const float*)d_in[6];
    const float* Wo   = (const float*)d_in[7];
    const float* bo   = (const float*)d_in[8];
    const float* We1  = (const float*)d_in[9];
    const float* be1  = (const float*)d_in[10];
    const float* We2  = (const float*)d_in[11];
    const float* be2  = (const float*)d_in[12];
    const float* Wn1  = (const float*)d_in[13];
    const float* bn1  = (const float*)d_in[14];
    const float* Wn2  = (const float*)d_in[15];
    const float* bn2  = (const float*)d_in[16];
    float* ws  = (float*)d_ws;
    float* out = (float*)d_out;

    prep_kernel<<<512, 256, 0, stream>>>(Wp, bp, Wi, bi, Wo, bo,
                                         We1, be1, We2, Wn2, ws);
    proj_kernel<<<512, 256, 0, stream>>>(node, ws);
    edge_kernel<<<1024, 512, 0, stream>>>(pos, sup, ws + OFF_AIN, ws + OFF_D,
                                          ws + OFF_COEF, be2, ws + OFF_PART);
    final_kernel<<<512, 256, 0, stream>>>(Wn1, bn1, ws + OFF_WN2T, bn2,
                                          ws + OFF_PART, out);
}

// Round 20
// 56.421 us; speedup vs baseline: 1.0594x; 1.0594x over previous
//
#include <hip/hip_runtime.h>
#include <hip/hip_bf16.h>

#define NN 512
#define FD 256
#define FI 128

typedef __attribute__((ext_vector_type(2))) float f2;

// workspace layout (float offsets)
#define OFF_AIN   0          // 2048*128  A_in = Uin x + biasIn
#define OFF_D     262144     // 2048*128  D    = -(Uout x + biasOut)
#define OFF_UINT  524288     // 64*128*4  (We1@Wi)^T packed [d4][g][4]
#define OFF_UOUTT 557056     // 64*128*4  (We1@Wo)^T packed [d4][g][4]
#define OFF_COEF  589824     // 32*16     per-gq packed {w0[4], w1[4], v[4], pad}
#define OFF_BIAS  590336     // 256       biasIn[128], biasOut[128]
#define OFF_PART  590592     // 1024*32   per-(b,jt,ir) partial maxes
#define OFF_WN2T  623360     // 64*256*4  Wn2 packed [d4][e][4]
// total 688896 floats = 2.63 MB

__device__ __forceinline__ f2 pk_fma(f2 a, f2 b, f2 c) {
    return __builtin_elementwise_fma(a, b, c);
}

// packed gelu pair: x * sigmoid(1.5958(x + 0.0447x^3)), log2e folded
__device__ __forceinline__ f2 gelu2(f2 x) {
    f2 x2 = x * x;
    f2 s  = pk_fma(x2, (f2)(0.10294325f), (f2)(2.3022083f));
    f2 zs = x * s;
    f2 e;
    e.x = __builtin_amdgcn_exp2f(zs.x);
    e.y = __builtin_amdgcn_exp2f(zs.y);
    f2 ep = e + (f2)(1.0f);
    f2 r;
    r.x = __builtin_amdgcn_rcpf(ep.x);
    r.y = __builtin_amdgcn_rcpf(ep.y);
    return pk_fma(-x, r, x);
}

// ---- kernel 1: fold U^T (packed [d4][g][4]) + pack Wn2 ----------------------
__global__ __launch_bounds__(256) void prep_kernel(
    const float* __restrict__ Wp,  const float* __restrict__ bp,
    const float* __restrict__ Wi,  const float* __restrict__ bi,
    const float* __restrict__ Wo,  const float* __restrict__ bo,
    const float* __restrict__ We1, const float* __restrict__ be1,
    const float* __restrict__ We2, const float* __restrict__ Wn2,
    float* ws)
{
    int bidx = blockIdx.x;
    int d = threadIdx.x;
    if (bidx >= 256) {                         // Wn2 transpose-pack
        int e = bidx - 256;                    // e in 0..255
        float v = Wn2[e * FD + d];             // coalesced row read
        ws[OFF_WN2T + (d >> 2) * (FD * 4) + e * 4 + (d & 3)] = v;
        return;
    }
    int io = bidx >> 7, g = bidx & 127;
    const float* W = io ? Wo : Wi;
    const float* wrow = We1 + g * FI;          // wave-uniform -> s_loads
    float acc = 0.f;
    for (int f = 0; f < FI; ++f)
        acc = __fmaf_rn(wrow[f], W[f * FD + d], acc);   // coalesced over d
    // packed layout [d4][g][4]
    ws[(io ? OFF_UOUTT : OFF_UINT) + (d >> 2) * (FI * 4) + g * 4 + (d & 3)] = acc;

    if (bidx == 0 && d < FI) {
        const float* wr = We1 + d * FI;
        float a0 = 0.f, a1 = 0.f, abi = 0.f, abo = 0.f;
        for (int f = 0; f < FI; ++f) {
            float w = wr[f];
            a0  = __fmaf_rn(w, Wp[f * 2 + 0], a0);
            a1  = __fmaf_rn(w, Wp[f * 2 + 1], a1);
            abi = __fmaf_rn(w, bi[f] + bp[f], abi);
            abo = __fmaf_rn(w, bo[f], abo);
        }
        int gq = d >> 2, k = d & 3;
        ws[OFF_COEF + gq * 16 + k]     = a0;
        ws[OFF_COEF + gq * 16 + 4 + k] = a1;
        ws[OFF_COEF + gq * 16 + 8 + k] = We2[d];
        ws[OFF_BIAS + d]       = abi + be1[d];
        ws[OFF_BIAS + 128 + d] = abo;
    }
}

// ---- kernel 2: node projections A/D — g-split, U read once per block --------
// 512 blocks = 256 node-octets x 2 g-halves; 256 thr; 2 blk/CU
__global__ __launch_bounds__(256) void proj_kernel(
    const float* __restrict__ x, float* ws)
{
    __shared__ __align__(16) float xs[8][FD];   // 8 KB
    int t  = threadIdx.x;
    int nb = (blockIdx.x >> 1) * 8;
    int h  = blockIdx.x & 1;
    ((float4*)xs)[t]       = ((const float4*)(x + nb * FD))[t];
    ((float4*)xs)[t + 256] = ((const float4*)(x + nb * FD))[t + 256];
    __syncthreads();

    int gl = t & 63, io = (t >> 6) & 1, nh = t >> 7;
    int g = h * 64 + gl;
    const float4* U4 = (const float4*)(ws + (io ? OFF_UOUTT : OFF_UINT));
    float bias = ws[OFF_BIAS + io * 128 + g];
    f2 acc[4];
    #pragma unroll
    for (int n = 0; n < 4; ++n) acc[n] = (f2)(0.f);

    #pragma unroll 4
    for (int d4 = 0; d4 < FD / 4; ++d4) {
        float4 u = U4[d4 * FI + g];            // coalesced 1 KB per wave
        f2 u01 = {u.x, u.y}, u23 = {u.z, u.w};
        #pragma unroll
        for (int n = 0; n < 4; ++n) {
            float4 xv = *(const float4*)(&xs[nh * 4 + n][d4 * 4]);  // bcast
            f2 x01 = {xv.x, xv.y}, x23 = {xv.z, xv.w};
            acc[n] = pk_fma(u01, x01, acc[n]);
            acc[n] = pk_fma(u23, x23, acc[n]);
        }
    }

    float sgn = io ? -1.f : 1.f;
    float* dst = ws + (io ? OFF_D : OFF_AIN);
    #pragma unroll
    for (int n = 0; n < 4; ++n)
        dst[(nb + nh * 4 + n) * FI + g] = sgn * (acc[n].x + acc[n].y + bias);
}

// ---- kernel 3: edge MLP on ACTIVE edges (packed-f32 inner loop) -------------
// 1024 blocks = 4b * 16jt * 16ir; tile = 32 i-rows x 32 j-cols; 512 threads
__global__ __launch_bounds__(512) void edge_kernel(
    const float* __restrict__ pos, const float* __restrict__ sup,
    const float* __restrict__ Ain, const float* __restrict__ Dmat,
    const float* __restrict__ coef, const float* __restrict__ be2p,
    float* __restrict__ part)
{
    __shared__ __align__(16) float sD[32 * 128];   // 16 KB, swizzle (r&31)<<2
    __shared__ __align__(16) float sA[32 * 128];   // 16 KB, swizzle (r&31)<<2
    __shared__ unsigned short sList[1024];         // 2 KB active-edge list
    __shared__ int smax[32];                       // per-j col max (float bits)
    __shared__ int scnt;                           // ~34.2 KB total

    int tile = blockIdx.x;
    int ir = tile & 15, jt = (tile >> 4) & 15, b = tile >> 8;  // 16*16*4 = 1024
    int tid = threadIdx.x;
    int lane = tid & 63;

    // stage D (32 j-rows): word = r*128 + (c ^ ((r&31)<<2))  [bijective in-row]
    const float4* Dg4 = (const float4*)(Dmat + (b * NN + jt * 32) * FI);
    #pragma unroll
    for (int k = 0; k < 2; ++k) {
        int s = tid + k * 512;
        float4 v = Dg4[s];
        int r = s >> 5, c = (s & 31) * 4;
        *(float4*)(sD + r * 128 + (c ^ ((r & 31) << 2))) = v;
    }
    // stage A (32 i-rows)
    const float4* Ag4 = (const float4*)(Ain + (b * NN + ir * 32) * FI);
    #pragma unroll
    for (int k = 0; k < 2; ++k) {
        int s = tid + k * 512;
        float4 v = Ag4[s];
        int r = s >> 5, c = (s & 31) * 4;
        *(float4*)(sA + r * 128 + (c ^ ((r & 31) << 2))) = v;
    }
    if (tid < 32) smax[tid] = 0;   // 0.0f == exact value of suppressed edges
    if (tid == 0) scnt = 0;
    __syncthreads();

    // compaction: 1024 candidates in 2 rounds; entries j-contiguous per i-row
    const float* S = sup + (size_t)(b * NN + ir * 32) * NN + jt * 32;
    #pragma unroll
    for (int k = 0; k < 2; ++k) {
        int s = tid + k * 512;
        int i_l = s >> 5, j_l = s & 31;
        bool act = (S[i_l * NN + j_l] != 0.f);
        unsigned long long mask = __ballot(act);
        int wbase = 0;
        if (lane == 0 && mask) wbase = atomicAdd(&scnt, (int)__popcll(mask));
        wbase = __shfl(wbase, 0);
        if (act) {
            int prefix = (int)__popcll(mask & ((1ull << lane) - 1ull));
            sList[wbase + prefix] = (unsigned short)s;
        }
    }
    __syncthreads();

    int cnt = scnt;
    float be2 = *be2p;
    const float2* pos2 = (const float2*)pos;

    for (int r = tid; r < cnt; r += 512) {
        int e = (int)sList[r];
        int i_l = e >> 5, j_l = e & 31;
        float2 pp = pos2[(size_t)(b * NN + ir * 32 + i_l) * NN + jt * 32 + j_l];
        const float* Ar = sA + i_l * 128;
        const float* Dr = sD + j_l * 128;
        int aswz = i_l << 2;           // i_l < 32
        int dswz = j_l << 2;           // j_l < 32
        f2 px = {pp.x, pp.x}, py = {pp.y, pp.y};
        f2 z01 = {0.f, 0.f}, z23 = {0.f, 0.f};
        #pragma unroll 4
        for (int gq = 0; gq < 32; ++gq) {
            float4 a  = *(const float4*)(Ar + ((gq * 4) ^ aswz));
            float4 d  = *(const float4*)(Dr + ((gq * 4) ^ dswz));
            // wave-uniform, loop-uniform -> s_load_dwordx4 into SGPRs
            float4 w0 = *(const float4*)(coef + gq * 16);
            float4 w1 = *(const float4*)(coef + gq * 16 + 4);
            float4 vv = *(const float4*)(coef + gq * 16 + 8);
            f2 a01 = {a.x, a.y}, a23 = {a.z, a.w};
            f2 d01 = {d.x, d.y}, d23 = {d.z, d.w};
            f2 w001 = {w0.x, w0.y}, w023 = {w0.z, w0.w};
            f2 w101 = {w1.x, w1.y}, w123 = {w1.z, w1.w};
            f2 v01 = {vv.x, vv.y}, v23 = {vv.z, vv.w};
            f2 y01 = pk_fma(w101, py, pk_fma(w001, px, a01 + d01));
            f2 y23 = pk_fma(w123, py, pk_fma(w023, px, a23 + d23));
            z01 = pk_fma(v01, gelu2(y01), z01);
            z23 = pk_fma(v23, gelu2(y23), z23);
        }
        float z = (z01.x + z01.y) + (z23.x + z23.y);
        // positive floats order-preserve as signed ints; negatives < 0 == init
        atomicMax(&smax[j_l], __float_as_int(z + be2));
    }
    __syncthreads();
    if (tid < 32)
        part[tile * 32 + tid] = __int_as_float(smax[tid]);
}

// ---- kernel 4: reduce 16 i-range partials + node FFN (packed-Wn2 reads) -----
// 512 blocks * 4 nodes
__global__ __launch_bounds__(256) void final_kernel(
    const float* __restrict__ Wn1, const float* __restrict__ bn1,
    const float* __restrict__ wtx, const float* __restrict__ bn2,
    const float* __restrict__ part, float* __restrict__ out)
{
    __shared__ float red[4][17];
    __shared__ float nm[4];
    __shared__ __align__(16) float h1[4][FD];
    int nb = blockIdx.x * 4;                  // 512 blocks * 4 nodes
    int b  = nb >> 9;
    int j0 = nb & 511;
    int jt = j0 >> 5, jl0 = j0 & 31;          // 4-aligned j0 stays in one jt
    int t = threadIdx.x;
    if (t < 64) {
        int k = t & 3, ir = t >> 2;           // ir in 0..15
        red[k][ir] = part[(((b * 16 + jt) * 16) + ir) * 32 + jl0 + k];
    }
    __syncthreads();
    if (t < 4) {
        float m2 = red[t][0];
        #pragma unroll
        for (int q = 1; q < 16; ++q) m2 = fmaxf(m2, red[t][q]);
        nm[t] = m2;
    }
    __syncthreads();
    {
        float wv = Wn1[t];        // Wn1 shape [256,1]
        float bv = bn1[t];
        #pragma unroll
        for (int n = 0; n < 4; ++n)
            h1[n][t] = fmaxf(0.f, __fmaf_rn(nm[n], wv, bv));
    }
    __syncthreads();
    float acc[4] = {0.f, 0.f, 0.f, 0.f};
    const float4* WX = (const float4*)wtx;    // [d4][e]
    #pragma unroll 4
    for (int d4 = 0; d4 < FD / 4; ++d4) {
        float4 w = WX[d4 * FD + t];           // coalesced 1 KB per wave
        #pragma unroll
        for (int n = 0; n < 4; ++n) {
            float4 hv = *(const float4*)(&h1[n][d4 * 4]);  // broadcast (free)
            acc[n] = __fmaf_rn(w.x, hv.x, acc[n]);
            acc[n] = __fmaf_rn(w.y, hv.y, acc[n]);
            acc[n] = __fmaf_rn(w.z, hv.z, acc[n]);
            acc[n] = __fmaf_rn(w.w, hv.w, acc[n]);
        }
    }
    float bb = bn2[t];
    #pragma unroll
    for (int n = 0; n < 4; ++n)
        out[(size_t)(nb + n) * FD + t] = fmaxf(0.f, acc[n] + bb);
}

extern "C" void kernel_launch(void* const* d_in, const int* in_sizes, int n_in,
                              void* d_out, int out_size, void* d_ws, size_t ws_size,
                              hipStream_t stream) {
    (void)in_sizes; (void)n_in; (void)out_size; (void)ws_size;
    const float* node = (const float*)d_in[0];
    const float* sup  = (const float*)d_in[1];
    const float* pos  = (const float*)d_in[2];
    const float* Wp   = (const float*)d_in[3];
    const float* bp   = (const float*)d_in[4];
    const float* Wi   = (const float*)d_in[5];
    const float* bi   = (const float*)d_in[6];
    const float* Wo   = (const float*)d_in[7];
    const float* bo   = (const float*)d_in[8];
    const float* We1  = (const float*)d_in[9];
    const float* be1  = (const float*)d_in[10];
    const float* We2  = (const float*)d_in[11];
    const float* be2  = (const float*)d_in[12];
    const float* Wn1  = (const float*)d_in[13];
    const float* bn1  = (const float*)d_in[14];
    const float* Wn2  = (const float*)d_in[15];
    const float* bn2  = (const float*)d_in[16];
    float* ws  = (float*)d_ws;
    float* out = (float*)d_out;

    prep_kernel<<<512, 256, 0, stream>>>(Wp, bp, Wi, bi, Wo, bo,
                                         We1, be1, We2, Wn2, ws);
    proj_kernel<<<512, 256, 0, stream>>>(node, ws);
    edge_kernel<<<1024, 512, 0, stream>>>(pos, sup, ws + OFF_AIN, ws + OFF_D,
                                          ws + OFF_COEF, be2, ws + OFF_PART);
    final_kernel<<<512, 256, 0, stream>>>(Wn1, bn1, ws + OFF_WN2T, bn2,
                                          ws + OFF_PART, out);
}